// Round 3
// baseline (714.265 us; speedup 1.0000x reference)
//
#include <hip/hip_runtime.h>
#include <hip/hip_bf16.h>
#include <hip/hip_fp16.h>

// B=8, T(N)=256, F=256, K=2, H=128, gates=512, 2H=256.
//
// Exact math simplifications (data-independent):
//  - LayerNorm over size-1 dim => logits == ln_adj_b (constant) => row softmax
//    => TG = 1/256 exactly, regardless of inputs.
//  - A_hat rowsum == 2.0 exactly => P@x = 0.5*x + colsum(x)/512
//    cheb out = x @ (W0 + 0.5*W1) + (colsum/512) @ W1 + cheb_b -> LayerNorm(256)
//  - BiLSTM: 2 dirs x 8 batch = 16 independent recurrences per layer.
//
// Robustness decisions this round:
//  - ws footprint cut to 7.27 MB (suspected ws_size ~8-16MB; rounds 1-2 OOB).
//  - No fp32 staging: kernels read raw inputs via flag-branched loader
//    (runtime bf16-vs-fp32 detector; branch is wave-uniform).
//  - Big intermediates (WT, cheb-out, hidden states, gin) stored fp16
//    (storage only; all arithmetic fp32; bf16 weights are exact in fp16).
//  - Buffer aliasing by lifetime: M1 = hbuf0 then lnout; M2 = hcat0 then hcat1.

typedef unsigned short u16;
typedef unsigned int u32;

__device__ __forceinline__ float bf2f(u16 v) { return __uint_as_float(((u32)v) << 16); }
__device__ __forceinline__ u16 f2bf(float f) {
    u32 u = __float_as_uint(f);
    u32 r = (u + 0x7fffu + ((u >> 16) & 1u)) >> 16;
    return (u16)r;
}
__device__ __forceinline__ float sigm(float x) { return 1.0f / (1.0f + __expf(-x)); }
__device__ __forceinline__ float tanh_f(float x) { return 1.0f - 2.0f / (__expf(2.0f * x) + 1.0f); }
// flag-branched raw input load (f32=1: fp32 buffer, else bf16)
__device__ __forceinline__ float ldin(const void* p, long long i, int f32) {
    return f32 ? ((const float*)p)[i] : bf2f(((const u16*)p)[i]);
}
__device__ __forceinline__ void store_out(void* out, long long idx, float v, int f32) {
    if (f32) ((float*)out)[idx] = v;
    else ((u16*)out)[idx] = f2bf(v);
}

// ---- ws layout (BYTE offsets), total 7,618,624 B = 7.27 MB -----------------
#define WB_FLAG 0
#define WB_S    64        // fp32 [2048]
#define WB_TB   8256      // fp32 [2048]
#define WB_WC   16448     // fp32 [65536]
#define WB_WT   278592    // fp16 [524288]  WihT staged
#define WB_M1   1327168   // fp16 [524288]  hbuf0 (cheb out), later lnout
#define WB_M2   2375744   // fp16 [524288]  hcat0, later hcat1
#define WB_GIN  3424320   // fp16 [2097152] gate inputs, one layer at a time

// ---- dtype detector: low u16 of fp32 words has random high mantissa bits ---
__global__ void k_detect(const u32* __restrict__ xraw, int* __restrict__ flag) {
    __shared__ int cnt;
    if (threadIdx.x == 0) cnt = 0;
    __syncthreads();
    u32 w = xraw[threadIdx.x];
    int e = (w >> 7) & 0xFF; // low u16 viewed as bf16: exponent field
    if (e >= 0x90) atomicAdd(&cnt, 1); // |x|>=2^17: impossible for real bf16 data
    __syncthreads();
    if (threadIdx.x == 0) *flag = (cnt > 32) ? 1 : 0; // 1 = fp32 inputs
}

// ---- TG = 1/256 everywhere -------------------------------------------------
__global__ void k_fill_tg(void* out, const int* __restrict__ flagp) {
    long long i = (long long)blockIdx.x * 256 + threadIdx.x;
    store_out(out, 2048 + i, 0.00390625f, *flagp);
}

// ---- S[b][f] = sum_n x[b][n][f] --------------------------------------------
__global__ void k_colsum(const void* __restrict__ x, float* __restrict__ S,
                         const int* __restrict__ flagp) {
    int f32 = *flagp;
    int b = blockIdx.x, f = threadIdx.x;
    float s = 0.f;
    for (int n = 0; n < 256; n++) s += ldin(x, (b * 256 + n) * 256 + f, f32);
    S[b * 256 + f] = s;
}

// ---- Wc = W0 + 0.5*W1 (fp32) -----------------------------------------------
__global__ void k_wc(const void* __restrict__ chw, float* __restrict__ Wc,
                     const int* __restrict__ flagp) {
    int f32 = *flagp;
    int i = blockIdx.x * 256 + threadIdx.x;
    Wc[i] = ldin(chw, i, f32) + 0.5f * ldin(chw, 65536 + i, f32);
}

// ---- tb[b][o] = cheb_b[o] + (S[b]/512) @ W1[:,o] ---------------------------
__global__ void k_tb(const float* __restrict__ S, const void* __restrict__ chw,
                     const void* __restrict__ chb, float* __restrict__ tb,
                     const int* __restrict__ flagp) {
    int f32 = *flagp;
    int b = blockIdx.x, o = threadIdx.x;
    float acc = ldin(chb, o, f32);
    const float cs = 1.0f / 512.0f;
    for (int f = 0; f < 256; f++)
        acc = fmaf(S[b * 256 + f] * cs, ldin(chw, 65536 + f * 256 + o, f32), acc);
    tb[b * 256 + o] = acc;
}

// ---- cheb row GEMM + LayerNorm(256) -> M1 fp16 -----------------------------
__global__ void k_cheb_ln(const void* __restrict__ x, const float* __restrict__ Wc,
                          const float* __restrict__ tb, const void* __restrict__ g,
                          const void* __restrict__ bb, __half* __restrict__ out,
                          const int* __restrict__ flagp) {
    __shared__ float xr[256];
    __shared__ float red1[4], red2[4];
    int f32 = *flagp;
    int row = blockIdx.x;
    int b = row >> 8;
    int o = threadIdx.x;
    xr[o] = ldin(x, row * 256 + o, f32);
    __syncthreads();
    float acc = tb[b * 256 + o];
    const float4* x4 = (const float4*)xr;
#pragma unroll 8
    for (int q = 0; q < 64; q++) {
        float4 xv = x4[q];
        int f = q * 4;
        acc = fmaf(xv.x, Wc[f * 256 + o], acc);
        acc = fmaf(xv.y, Wc[(f + 1) * 256 + o], acc);
        acc = fmaf(xv.z, Wc[(f + 2) * 256 + o], acc);
        acc = fmaf(xv.w, Wc[(f + 3) * 256 + o], acc);
    }
    float s1 = acc, s2 = acc * acc;
    for (int off = 32; off >= 1; off >>= 1) {
        s1 += __shfl_xor(s1, off, 64);
        s2 += __shfl_xor(s2, off, 64);
    }
    if ((o & 63) == 0) { red1[o >> 6] = s1; red2[o >> 6] = s2; }
    __syncthreads();
    float S1 = red1[0] + red1[1] + red1[2] + red1[3];
    float S2 = red2[0] + red2[1] + red2[2] + red2[3];
    float m = S1 * (1.0f / 256.0f);
    float var = S2 * (1.0f / 256.0f) - m * m;
    float rstd = rsqrtf(var + 1e-5f);
    out[row * 256 + o] = __float2half((acc - m) * rstd * ldin(g, o, f32) + ldin(bb, o, f32));
}

// ---- WT[ld][f][j] = wih[ld][j][f] (fp16) -----------------------------------
__global__ void k_wih_t(const void* __restrict__ wih, __half* __restrict__ WT,
                        const int* __restrict__ flagp) {
    int f32 = *flagp;
    int ld = blockIdx.y;
    int f = blockIdx.x;
    int j = threadIdx.x;
    WT[ld * 131072 + f * 512 + j] = __float2half(ldin(wih, (ld * 512 + j) * 256 + f, f32));
}

// ---- gin[d][b][t][j] = in[b][t] @ WihT + bih + bhh (fp16 store) ------------
__global__ __launch_bounds__(512) void k_gin(const __half* __restrict__ in,
                                             const __half* __restrict__ WT,
                                             const void* __restrict__ bih,
                                             const void* __restrict__ bhh,
                                             __half* __restrict__ gin, int l,
                                             const int* __restrict__ flagp) {
    __shared__ float inl[16 * 256];
    int f32 = *flagp;
    int d = blockIdx.x >> 7;
    int rb = (blockIdx.x & 127) * 16; // 16 rows of (b,t) space, same b
    int j = threadIdx.x;
    const __half2* src = (const __half2*)(in + (size_t)rb * 256); // 2048 half2
    float2* dst = (float2*)inl;
#pragma unroll
    for (int q = 0; q < 4; q++)
        dst[j + q * 512] = __half22float2(src[j + q * 512]);
    __syncthreads();
    int ld = l * 2 + d;
    float bias = ldin(bih, ld * 512 + j, f32) + ldin(bhh, ld * 512 + j, f32);
    float acc[16];
#pragma unroll
    for (int r = 0; r < 16; r++) acc[r] = bias;
    const __half* W = WT + (size_t)ld * 131072;
    for (int fq = 0; fq < 64; fq++) {
        int f = fq * 4;
        float w0 = __half2float(W[(f + 0) * 512 + j]);
        float w1 = __half2float(W[(f + 1) * 512 + j]);
        float w2 = __half2float(W[(f + 2) * 512 + j]);
        float w3 = __half2float(W[(f + 3) * 512 + j]);
#pragma unroll
        for (int r = 0; r < 16; r++) {
            const float4 iv = ((const float4*)(inl + r * 256))[fq];
            acc[r] = fmaf(iv.x, w0, fmaf(iv.y, w1, fmaf(iv.z, w2, fmaf(iv.w, w3, acc[r]))));
        }
    }
    int b = rb >> 8;
    int t0 = rb & 255;
#pragma unroll
    for (int r = 0; r < 16; r++)
        gin[(size_t)(((d * 8 + b) * 256) + (t0 + r)) * 512 + j] = __float2half(acc[r]);
}

// ---- LSTM recurrence: one block per (dir, batch) ---------------------------
__global__ __launch_bounds__(512, 2) void k_lstm(const __half* __restrict__ gin,
                                                 const void* __restrict__ whh,
                                                 long long woff, __half* __restrict__ hcat,
                                                 const int* __restrict__ flagp) {
    __shared__ float h_lds[128];
    __shared__ float gate[512];
    int f32 = *flagp;
    int d = blockIdx.x >> 3;
    int b = blockIdx.x & 7;
    int j = threadIdx.x;

    // Whh row j (128 weights) -> registers, fp32
    float w[128];
    if (f32) {
        const float4* p = (const float4*)((const float*)whh + woff + (size_t)(d * 512 + j) * 128);
#pragma unroll
        for (int q = 0; q < 32; q++) {
            float4 u = p[q];
            w[q * 4 + 0] = u.x; w[q * 4 + 1] = u.y; w[q * 4 + 2] = u.z; w[q * 4 + 3] = u.w;
        }
    } else {
        const uint4* p = (const uint4*)((const u16*)whh + woff + (size_t)(d * 512 + j) * 128);
#pragma unroll
        for (int q = 0; q < 16; q++) {
            uint4 u = p[q];
            w[q * 8 + 0] = __uint_as_float(u.x << 16);
            w[q * 8 + 1] = __uint_as_float(u.x & 0xffff0000u);
            w[q * 8 + 2] = __uint_as_float(u.y << 16);
            w[q * 8 + 3] = __uint_as_float(u.y & 0xffff0000u);
            w[q * 8 + 4] = __uint_as_float(u.z << 16);
            w[q * 8 + 5] = __uint_as_float(u.z & 0xffff0000u);
            w[q * 8 + 6] = __uint_as_float(u.w << 16);
            w[q * 8 + 7] = __uint_as_float(u.w & 0xffff0000u);
        }
    }

    if (j < 128) h_lds[j] = 0.0f;
    float c = 0.0f;
    const __half* gbase = gin + (size_t)((d * 8 + b) * 256) * 512 + j;
    __syncthreads();

    for (int t = 0; t < 256; t++) {
        int tt = d ? (255 - t) : t;
        float gv = __half2float(gbase[(size_t)tt * 512]);
        float acc = 0.0f;
        const float4* h4 = (const float4*)h_lds;
#pragma unroll
        for (int q = 0; q < 32; q++) {
            float4 hh = h4[q];
            acc = fmaf(hh.x, w[q * 4 + 0], acc);
            acc = fmaf(hh.y, w[q * 4 + 1], acc);
            acc = fmaf(hh.z, w[q * 4 + 2], acc);
            acc = fmaf(hh.w, w[q * 4 + 3], acc);
        }
        gate[j] = acc + gv;
        __syncthreads();
        if (j < 128) {
            float iv = gate[j], fv = gate[j + 128], gg = gate[j + 256], ov = gate[j + 384];
            c = sigm(fv) * c + sigm(iv) * tanh_f(gg);
            float hv = sigm(ov) * tanh_f(c);
            h_lds[j] = hv;
            hcat[(size_t)(b * 256 + tt) * 256 + d * 128 + j] = __float2half(hv);
        }
        __syncthreads();
    }
}

// ---- final LayerNorm(256): M2 -> M1 (lnout fp16) + output 2 ----------------
__global__ void k_ln_out(const __half* __restrict__ in, const void* __restrict__ g,
                         const void* __restrict__ bb, __half* __restrict__ lnout,
                         void* out, const int* __restrict__ flagp) {
    __shared__ float red1[4], red2[4];
    int f32 = *flagp;
    int row = blockIdx.x;
    int o = threadIdx.x;
    float v = __half2float(in[row * 256 + o]);
    float s1 = v, s2 = v * v;
    for (int off = 32; off >= 1; off >>= 1) {
        s1 += __shfl_xor(s1, off, 64);
        s2 += __shfl_xor(s2, off, 64);
    }
    if ((o & 63) == 0) { red1[o >> 6] = s1; red2[o >> 6] = s2; }
    __syncthreads();
    float S1 = red1[0] + red1[1] + red1[2] + red1[3];
    float S2 = red2[0] + red2[1] + red2[2] + red2[3];
    float m = S1 * (1.0f / 256.0f);
    float var = S2 * (1.0f / 256.0f) - m * m;
    float rstd = rsqrtf(var + 1e-5f);
    float r = (v - m) * rstd * ldin(g, o, f32) + ldin(bb, o, f32);
    lnout[row * 256 + o] = __float2half(r);
    store_out(out, 526336LL + (long long)row * 256 + o, r, f32);
}

// ---- agg[b][j] = mean_t lnout[b][t][j] -> output 0 -------------------------
__global__ void k_agg(const __half* __restrict__ lnout, void* out,
                      const int* __restrict__ flagp) {
    int b = blockIdx.x, j = threadIdx.x;
    float s = 0.f;
    for (int t = 0; t < 256; t++) s += __half2float(lnout[(size_t)(b * 256 + t) * 256 + j]);
    store_out(out, (long long)b * 256 + j, s * (1.0f / 256.0f), *flagp);
}

extern "C" void kernel_launch(void* const* d_in, const int* in_sizes, int n_in,
                              void* d_out, int out_size, void* d_ws, size_t ws_size,
                              hipStream_t stream) {
    char* wsb = (char*)d_ws;
    int*    flag = (int*)(wsb + WB_FLAG);
    float*  S    = (float*)(wsb + WB_S);
    float*  tb   = (float*)(wsb + WB_TB);
    float*  Wc   = (float*)(wsb + WB_WC);
    __half* WT   = (__half*)(wsb + WB_WT);
    __half* M1   = (__half*)(wsb + WB_M1);  // hbuf0, later lnout
    __half* M2   = (__half*)(wsb + WB_M2);  // hcat0, later hcat1
    __half* GIN  = (__half*)(wsb + WB_GIN);

    const void* x   = d_in[0];
    const void* chw = d_in[5];
    const void* chb = d_in[6];
    const void* lcg = d_in[7];
    const void* lcb = d_in[8];
    const void* wih = d_in[9];
    const void* whh = d_in[10];
    const void* bih = d_in[11];
    const void* bhh = d_in[12];
    const void* log_ = d_in[13];
    const void* lob  = d_in[14];

    k_detect<<<1, 256, 0, stream>>>((const u32*)x, flag);
    k_fill_tg<<<2048, 256, 0, stream>>>(d_out, flag);
    k_colsum<<<8, 256, 0, stream>>>(x, S, flag);
    k_wc<<<256, 256, 0, stream>>>(chw, Wc, flag);
    k_tb<<<8, 256, 0, stream>>>(S, chw, chb, tb, flag);
    k_cheb_ln<<<2048, 256, 0, stream>>>(x, Wc, tb, lcg, lcb, M1, flag);
    k_wih_t<<<dim3(256, 4), 512, 0, stream>>>(wih, WT, flag);
    // layer 0
    k_gin<<<256, 512, 0, stream>>>(M1, WT, bih, bhh, GIN, 0, flag);
    k_lstm<<<16, 512, 0, stream>>>(GIN, whh, 0LL, M2, flag);
    // layer 1 (reads M2=hcat0, overwrites M2 with hcat1 — hcat0 consumed by k_gin)
    k_gin<<<256, 512, 0, stream>>>(M2, WT, bih, bhh, GIN, 1, flag);
    k_lstm<<<16, 512, 0, stream>>>(GIN, whh, 131072LL, M2, flag);
    k_ln_out<<<2048, 256, 0, stream>>>(M2, log_, lob, M1, d_out, flag);
    k_agg<<<8, 256, 0, stream>>>(M1, d_out, flag);
}

// Round 4
// 643.924 us; speedup vs baseline: 1.1092x; 1.1092x over previous
//
#include <hip/hip_runtime.h>
#include <hip/hip_bf16.h>
#include <hip/hip_fp16.h>

// B=8, T(N)=256, F=256, K=2, H=128, gates=512, 2H=256.
//
// Exact math simplifications (data-independent):
//  - LayerNorm over size-1 dim => logits == ln_adj_b (constant) => row softmax
//    => TG = 1/256 exactly, regardless of inputs.
//  - A_hat rowsum == 2.0 exactly => P@x = 0.5*x + colsum(x)/512
//    cheb out = x @ (W0 + 0.5*W1) + (colsum/512) @ W1 + cheb_b -> LayerNorm(256)
//  - BiLSTM: 2 dirs x 8 batch = 16 independent recurrences per layer.
//
// R3->R4: k_lstm rewritten (pk_fma, distributed pre-activation, batched
// global h-stores); coalesced wih transpose; vectorized fill; split colsum.

typedef unsigned short u16;
typedef unsigned int u32;
typedef float v2f __attribute__((ext_vector_type(2)));

__device__ __forceinline__ float bf2f(u16 v) { return __uint_as_float(((u32)v) << 16); }
__device__ __forceinline__ u16 f2bf(float f) {
    u32 u = __float_as_uint(f);
    u32 r = (u + 0x7fffu + ((u >> 16) & 1u)) >> 16;
    return (u16)r;
}
__device__ __forceinline__ float sigm(float x) { return 1.0f / (1.0f + __expf(-x)); }
__device__ __forceinline__ float tanh_f(float x) { return 1.0f - 2.0f / (__expf(2.0f * x) + 1.0f); }
__device__ __forceinline__ float ldin(const void* p, long long i, int f32) {
    return f32 ? ((const float*)p)[i] : bf2f(((const u16*)p)[i]);
}
__device__ __forceinline__ void store_out(void* out, long long idx, float v, int f32) {
    if (f32) ((float*)out)[idx] = v;
    else ((u16*)out)[idx] = f2bf(v);
}

// ---- ws layout (BYTE offsets), total ~7.29 MB ------------------------------
#define WB_FLAG 0
#define WB_S    64        // fp32 [8192]  colsum partials (32 x 256)
#define WB_TB   32832     // fp32 [2048]
#define WB_WC   41024     // fp32 [65536]
#define WB_WT   303168    // fp16 [524288]  WihT
#define WB_M1   1351744   // fp16 [524288]  hbuf0 (cheb out), later lnout
#define WB_M2   2400320   // fp16 [524288]  hcat0, later hcat1
#define WB_GIN  3448896   // fp16 [2097152] gate inputs, one layer at a time

// ---- dtype detector --------------------------------------------------------
__global__ void k_detect(const u32* __restrict__ xraw, int* __restrict__ flag) {
    __shared__ int cnt;
    if (threadIdx.x == 0) cnt = 0;
    __syncthreads();
    u32 w = xraw[threadIdx.x];
    int e = (w >> 7) & 0xFF;
    if (e >= 0x90) atomicAdd(&cnt, 1);
    __syncthreads();
    if (threadIdx.x == 0) *flag = (cnt > 32) ? 1 : 0; // 1 = fp32 inputs
}

// ---- TG = 1/256 everywhere (4 elems/thread) --------------------------------
__global__ void k_fill_tg(void* out, const int* __restrict__ flagp) {
    int f32 = *flagp;
    long long i = (long long)blockIdx.x * 256 + threadIdx.x;
    if (f32) {
        float4 v{0.00390625f, 0.00390625f, 0.00390625f, 0.00390625f};
        ((float4*)((float*)out + 2048))[i] = v;
    } else {
        uint2 v{0x3B803B80u, 0x3B803B80u};
        ((uint2*)((u16*)out + 2048))[i] = v;
    }
}

// ---- colsum partials: Sp[b*4+ch][f] = sum over 64 rows ---------------------
__global__ void k_colsum(const void* __restrict__ x, float* __restrict__ Sp,
                         const int* __restrict__ flagp) {
    int f32 = *flagp;
    int blk = blockIdx.x;
    int b = blk >> 2, ch = blk & 3;
    int f = threadIdx.x;
    float s = 0.f;
    int n0 = ch * 64;
    for (int n = n0; n < n0 + 64; n++) s += ldin(x, ((long long)(b * 256 + n)) * 256 + f, f32);
    Sp[blk * 256 + f] = s;
}

// ---- Wc = W0 + 0.5*W1 (fp32) -----------------------------------------------
__global__ void k_wc(const void* __restrict__ chw, float* __restrict__ Wc,
                     const int* __restrict__ flagp) {
    int f32 = *flagp;
    int i = blockIdx.x * 256 + threadIdx.x;
    Wc[i] = ldin(chw, i, f32) + 0.5f * ldin(chw, 65536 + i, f32);
}

// ---- tb[b][o] = cheb_b[o] + (S[b]/512) @ W1[:,o] (merges colsum partials) --
__global__ void k_tb(const float* __restrict__ Sp, const void* __restrict__ chw,
                     const void* __restrict__ chb, float* __restrict__ tb,
                     const int* __restrict__ flagp) {
    int f32 = *flagp;
    int b = blockIdx.x, o = threadIdx.x;
    float acc = ldin(chb, o, f32);
    const float cs = 1.0f / 512.0f;
    for (int f = 0; f < 256; f++) {
        float s = Sp[(b * 4 + 0) * 256 + f] + Sp[(b * 4 + 1) * 256 + f] +
                  Sp[(b * 4 + 2) * 256 + f] + Sp[(b * 4 + 3) * 256 + f];
        acc = fmaf(s * cs, ldin(chw, 65536 + f * 256 + o, f32), acc);
    }
    tb[b * 256 + o] = acc;
}

// ---- cheb row GEMM + LayerNorm(256) -> M1 fp16 -----------------------------
__global__ void k_cheb_ln(const void* __restrict__ x, const float* __restrict__ Wc,
                          const float* __restrict__ tb, const void* __restrict__ g,
                          const void* __restrict__ bb, __half* __restrict__ out,
                          const int* __restrict__ flagp) {
    __shared__ float xr[256];
    __shared__ float red1[4], red2[4];
    int f32 = *flagp;
    int row = blockIdx.x;
    int b = row >> 8;
    int o = threadIdx.x;
    xr[o] = ldin(x, row * 256 + o, f32);
    __syncthreads();
    float acc = tb[b * 256 + o];
    const float4* x4 = (const float4*)xr;
#pragma unroll 8
    for (int q = 0; q < 64; q++) {
        float4 xv = x4[q];
        int f = q * 4;
        acc = fmaf(xv.x, Wc[f * 256 + o], acc);
        acc = fmaf(xv.y, Wc[(f + 1) * 256 + o], acc);
        acc = fmaf(xv.z, Wc[(f + 2) * 256 + o], acc);
        acc = fmaf(xv.w, Wc[(f + 3) * 256 + o], acc);
    }
    float s1 = acc, s2 = acc * acc;
    for (int off = 32; off >= 1; off >>= 1) {
        s1 += __shfl_xor(s1, off, 64);
        s2 += __shfl_xor(s2, off, 64);
    }
    if ((o & 63) == 0) { red1[o >> 6] = s1; red2[o >> 6] = s2; }
    __syncthreads();
    float S1 = red1[0] + red1[1] + red1[2] + red1[3];
    float S2 = red2[0] + red2[1] + red2[2] + red2[3];
    float m = S1 * (1.0f / 256.0f);
    float var = S2 * (1.0f / 256.0f) - m * m;
    float rstd = rsqrtf(var + 1e-5f);
    out[row * 256 + o] = __float2half((acc - m) * rstd * ldin(g, o, f32) + ldin(bb, o, f32));
}

// ---- coalesced tiled transpose: WT[ld][f][j] = wih[ld][j][f] (fp16) --------
__global__ void k_wih_t(const void* __restrict__ wih, __half* __restrict__ WT,
                        const int* __restrict__ flagp) {
    __shared__ __half tile[64][65];
    int f32 = *flagp;
    int ld = blockIdx.z;
    int jt = blockIdx.y * 64;
    int ft = blockIdx.x * 64;
    int lane = threadIdx.x & 63;
    int wv = threadIdx.x >> 6;
#pragma unroll
    for (int r = wv; r < 64; r += 4)
        tile[r][lane] = __float2half(ldin(wih, ((long long)(ld * 512 + jt + r)) * 256 + ft + lane, f32));
    __syncthreads();
#pragma unroll
    for (int r = wv; r < 64; r += 4)
        WT[((long long)ld * 256 + ft + r) * 512 + jt + lane] = tile[lane][r];
}

// ---- gin[d][b][t][j] = in[b][t] @ WihT + bih + bhh (fp16 store) ------------
__global__ __launch_bounds__(512) void k_gin(const __half* __restrict__ in,
                                             const __half* __restrict__ WT,
                                             const void* __restrict__ bih,
                                             const void* __restrict__ bhh,
                                             __half* __restrict__ gin, int l,
                                             const int* __restrict__ flagp) {
    __shared__ float inl[16 * 256];
    int f32 = *flagp;
    int d = blockIdx.x >> 7;
    int rb = (blockIdx.x & 127) * 16;
    int j = threadIdx.x;
    const __half2* src = (const __half2*)(in + (size_t)rb * 256);
    float2* dst = (float2*)inl;
#pragma unroll
    for (int q = 0; q < 4; q++)
        dst[j + q * 512] = __half22float2(src[j + q * 512]);
    __syncthreads();
    int ld = l * 2 + d;
    float bias = ldin(bih, ld * 512 + j, f32) + ldin(bhh, ld * 512 + j, f32);
    float acc[16];
#pragma unroll
    for (int r = 0; r < 16; r++) acc[r] = bias;
    const __half* W = WT + (size_t)ld * 131072;
    for (int fq = 0; fq < 64; fq++) {
        int f = fq * 4;
        float w0 = __half2float(W[(f + 0) * 512 + j]);
        float w1 = __half2float(W[(f + 1) * 512 + j]);
        float w2 = __half2float(W[(f + 2) * 512 + j]);
        float w3 = __half2float(W[(f + 3) * 512 + j]);
#pragma unroll
        for (int r = 0; r < 16; r++) {
            const float4 iv = ((const float4*)(inl + r * 256))[fq];
            acc[r] = fmaf(iv.x, w0, fmaf(iv.y, w1, fmaf(iv.z, w2, fmaf(iv.w, w3, acc[r]))));
        }
    }
    int b = rb >> 8;
    int t0 = rb & 255;
#pragma unroll
    for (int r = 0; r < 16; r++)
        gin[(size_t)(((d * 8 + b) * 256) + (t0 + r)) * 512 + j] = __float2half(acc[r]);
}

// ---- LSTM recurrence: one block per (dir, batch) ---------------------------
// 512 thr = 1 gate column each. pk_fma GEMV; per-gate pre-activation by all
// waves; reducer (tid<128) does c/h update with a single tanh; h-history
// global stores batched 8 steps per burst to amortize barrier vmcnt drain.
__global__ __launch_bounds__(512) __attribute__((amdgpu_waves_per_eu(1, 2)))
void k_lstm(const __half* __restrict__ gin, const void* __restrict__ whh,
            long long woff, __half* __restrict__ hcat, const int* __restrict__ flagp) {
    __shared__ float h_lds[2][128];
    __shared__ float gate[512];
    int f32 = *flagp;
    int d = blockIdx.x >> 3;
    int b = blockIdx.x & 7;
    int tid = threadIdx.x;
    int gtype = tid >> 7; // 0:i 1:f 2:g 3:o

    v2f w2[64];
    if (f32) {
        const float2* p = (const float2*)((const float*)whh + woff + (size_t)(d * 512 + tid) * 128);
#pragma unroll
        for (int q = 0; q < 64; q++) { float2 u = p[q]; w2[q] = v2f{u.x, u.y}; }
    } else {
        const u32* p = (const u32*)((const u16*)whh + woff + (size_t)(d * 512 + tid) * 128);
#pragma unroll
        for (int q = 0; q < 64; q++) {
            u32 u = p[q];
            w2[q] = v2f{__uint_as_float(u << 16), __uint_as_float(u & 0xffff0000u)};
        }
    }

    if (tid < 128) h_lds[0][tid] = 0.0f;
    float c = 0.0f;
    float hv8[8];
    const __half* gbase = gin + (size_t)((d * 8 + b) * 256) * 512 + tid;
    __syncthreads();

    int cur = 0;
    for (int t8 = 0; t8 < 32; t8++) {
#pragma unroll
        for (int s = 0; s < 8; s++) {
            int t = t8 * 8 + s;
            int tt = d ? (255 - t) : t;
            float gv = __half2float(gbase[(size_t)tt * 512]);
            v2f a0{0.f, 0.f}, a1{0.f, 0.f};
            const float4* h4 = (const float4*)h_lds[cur];
#pragma unroll
            for (int q = 0; q < 32; q++) {
                float4 hh = h4[q];
                v2f hlo{hh.x, hh.y}, hhi{hh.z, hh.w};
                a0 = __builtin_elementwise_fma(hlo, w2[q * 2], a0);
                a1 = __builtin_elementwise_fma(hhi, w2[q * 2 + 1], a1);
            }
            float pre = a0.x + a0.y + a1.x + a1.y + gv;
            gate[tid] = (gtype == 2) ? tanh_f(pre) : sigm(pre);
            __syncthreads();
            if (tid < 128) {
                c = gate[tid + 128] * c + gate[tid] * gate[tid + 256];
                float hv = gate[tid + 384] * tanh_f(c);
                h_lds[cur ^ 1][tid] = hv;
                hv8[s] = hv;
            }
            __syncthreads();
            cur ^= 1;
        }
        // batched global stores (one vmcnt drain per 8 steps)
        if (tid < 128) {
            int tbase = t8 * 8;
#pragma unroll
            for (int s = 0; s < 8; s++) {
                int tt = d ? (255 - (tbase + s)) : (tbase + s);
                hcat[(size_t)(b * 256 + tt) * 256 + d * 128 + tid] = __float2half(hv8[s]);
            }
        }
    }
}

// ---- final LayerNorm(256): M2 -> M1 (lnout fp16) + output 2 ----------------
__global__ void k_ln_out(const __half* __restrict__ in, const void* __restrict__ g,
                         const void* __restrict__ bb, __half* __restrict__ lnout,
                         void* out, const int* __restrict__ flagp) {
    __shared__ float red1[4], red2[4];
    int f32 = *flagp;
    int row = blockIdx.x;
    int o = threadIdx.x;
    float v = __half2float(in[row * 256 + o]);
    float s1 = v, s2 = v * v;
    for (int off = 32; off >= 1; off >>= 1) {
        s1 += __shfl_xor(s1, off, 64);
        s2 += __shfl_xor(s2, off, 64);
    }
    if ((o & 63) == 0) { red1[o >> 6] = s1; red2[o >> 6] = s2; }
    __syncthreads();
    float S1 = red1[0] + red1[1] + red1[2] + red1[3];
    float S2 = red2[0] + red2[1] + red2[2] + red2[3];
    float m = S1 * (1.0f / 256.0f);
    float var = S2 * (1.0f / 256.0f) - m * m;
    float rstd = rsqrtf(var + 1e-5f);
    float r = (v - m) * rstd * ldin(g, o, f32) + ldin(bb, o, f32);
    lnout[row * 256 + o] = __float2half(r);
    store_out(out, 526336LL + (long long)row * 256 + o, r, f32);
}

// ---- agg[b][j] = mean_t lnout[b][t][j] -> output 0 -------------------------
__global__ void k_agg(const __half* __restrict__ lnout, void* out,
                      const int* __restrict__ flagp) {
    int b = blockIdx.x, j = threadIdx.x;
    float s = 0.f;
    for (int t = 0; t < 256; t++) s += __half2float(lnout[(size_t)(b * 256 + t) * 256 + j]);
    store_out(out, (long long)b * 256 + j, s * (1.0f / 256.0f), *flagp);
}

extern "C" void kernel_launch(void* const* d_in, const int* in_sizes, int n_in,
                              void* d_out, int out_size, void* d_ws, size_t ws_size,
                              hipStream_t stream) {
    char* wsb = (char*)d_ws;
    int*    flag = (int*)(wsb + WB_FLAG);
    float*  Sp   = (float*)(wsb + WB_S);
    float*  tb   = (float*)(wsb + WB_TB);
    float*  Wc   = (float*)(wsb + WB_WC);
    __half* WT   = (__half*)(wsb + WB_WT);
    __half* M1   = (__half*)(wsb + WB_M1);
    __half* M2   = (__half*)(wsb + WB_M2);
    __half* GIN  = (__half*)(wsb + WB_GIN);

    const void* x   = d_in[0];
    const void* chw = d_in[5];
    const void* chb = d_in[6];
    const void* lcg = d_in[7];
    const void* lcb = d_in[8];
    const void* wih = d_in[9];
    const void* whh = d_in[10];
    const void* bih = d_in[11];
    const void* bhh = d_in[12];
    const void* log_ = d_in[13];
    const void* lob  = d_in[14];

    k_detect<<<1, 256, 0, stream>>>((const u32*)x, flag);
    k_fill_tg<<<512, 256, 0, stream>>>(d_out, flag);
    k_colsum<<<32, 256, 0, stream>>>(x, Sp, flag);
    k_wc<<<256, 256, 0, stream>>>(chw, Wc, flag);
    k_tb<<<8, 256, 0, stream>>>(Sp, chw, chb, tb, flag);
    k_cheb_ln<<<2048, 256, 0, stream>>>(x, Wc, tb, lcg, lcb, M1, flag);
    k_wih_t<<<dim3(4, 8, 4), 256, 0, stream>>>(wih, WT, flag);
    // layer 0
    k_gin<<<256, 512, 0, stream>>>(M1, WT, bih, bhh, GIN, 0, flag);
    k_lstm<<<16, 512, 0, stream>>>(GIN, whh, 0LL, M2, flag);
    // layer 1
    k_gin<<<256, 512, 0, stream>>>(M2, WT, bih, bhh, GIN, 1, flag);
    k_lstm<<<16, 512, 0, stream>>>(GIN, whh, 131072LL, M2, flag);
    k_ln_out<<<2048, 256, 0, stream>>>(M2, log_, lob, M1, d_out, flag);
    k_agg<<<8, 256, 0, stream>>>(M1, d_out, flag);
}

// Round 5
// 544.949 us; speedup vs baseline: 1.3107x; 1.1816x over previous
//
#include <hip/hip_runtime.h>
#include <hip/hip_bf16.h>
#include <hip/hip_fp16.h>

// B=8, T(N)=256, F=256, K=2, H=128, gates=512, 2H=256.
//
// Exact math simplifications (data-independent):
//  - LayerNorm over size-1 dim => logits == ln_adj_b (constant) => row softmax
//    => TG = 1/256 exactly, regardless of inputs.
//  - A_hat rowsum == 2.0 exactly => P@x = 0.5*x + colsum(x)/512
//    cheb out = x @ (W0 + 0.5*W1) + (colsum/512) @ W1 + cheb_b -> LayerNorm(256)
//  - BiLSTM: 2 dirs x 8 batch = 16 independent recurrences per layer.
//
// R4->R5: k_lstm is LDS-return-BW bound (broadcast ds_read_b128 writes
// 1024B/instr to VGPRs). Fix: h stored fp16 in LDS + v_dot2_f32_f16
// (halves both LDS instrs and bytes; no unpack VALU). k_tb split 64+8 blocks.

typedef unsigned short u16;
typedef unsigned int u32;
typedef _Float16 h2_t __attribute__((ext_vector_type(2)));

__device__ __forceinline__ float bf2f(u16 v) { return __uint_as_float(((u32)v) << 16); }
__device__ __forceinline__ u16 f2bf(float f) {
    u32 u = __float_as_uint(f);
    u32 r = (u + 0x7fffu + ((u >> 16) & 1u)) >> 16;
    return (u16)r;
}
__device__ __forceinline__ float sigm(float x) { return 1.0f / (1.0f + __expf(-x)); }
__device__ __forceinline__ float tanh_f(float x) { return 1.0f - 2.0f / (__expf(2.0f * x) + 1.0f); }
__device__ __forceinline__ float ldin(const void* p, long long i, int f32) {
    return f32 ? ((const float*)p)[i] : bf2f(((const u16*)p)[i]);
}
__device__ __forceinline__ void store_out(void* out, long long idx, float v, int f32) {
    if (f32) ((float*)out)[idx] = v;
    else ((u16*)out)[idx] = f2bf(v);
}
__device__ __forceinline__ h2_t as_h2(u32 w) { return __builtin_bit_cast(h2_t, w); }

// ---- ws layout (BYTE offsets), total ~7.35 MB ------------------------------
#define WB_FLAG 0
#define WB_S    64        // fp32 [8192]   colsum partials (32 x 256)
#define WB_TB   32832     // fp32 [2048]
#define WB_TBP  41024     // fp32 [16384]  tb partials (64 x 256)
#define WB_WC   106560    // fp32 [65536]
#define WB_WT   368704    // fp16 [524288] WihT
#define WB_M1   1417280   // fp16 [524288] hbuf0 (cheb out), later lnout
#define WB_M2   2465856   // fp16 [524288] hcat0, later hcat1
#define WB_GIN  3514432   // fp16 [2097152] gate inputs, one layer at a time

// ---- dtype detector --------------------------------------------------------
__global__ void k_detect(const u32* __restrict__ xraw, int* __restrict__ flag) {
    __shared__ int cnt;
    if (threadIdx.x == 0) cnt = 0;
    __syncthreads();
    u32 w = xraw[threadIdx.x];
    int e = (w >> 7) & 0xFF;
    if (e >= 0x90) atomicAdd(&cnt, 1);
    __syncthreads();
    if (threadIdx.x == 0) *flag = (cnt > 32) ? 1 : 0; // 1 = fp32 inputs
}

// ---- TG = 1/256 everywhere -------------------------------------------------
__global__ void k_fill_tg(void* out, const int* __restrict__ flagp) {
    int f32 = *flagp;
    long long i = (long long)blockIdx.x * 256 + threadIdx.x;
    if (f32) {
        float4 v{0.00390625f, 0.00390625f, 0.00390625f, 0.00390625f};
        ((float4*)((float*)out + 2048))[i] = v;
    } else {
        uint2 v{0x3B803B80u, 0x3B803B80u};
        ((uint2*)((u16*)out + 2048))[i] = v;
    }
}

// ---- colsum partials: Sp[b*4+ch][f] = sum over 64 rows ---------------------
__global__ void k_colsum(const void* __restrict__ x, float* __restrict__ Sp,
                         const int* __restrict__ flagp) {
    int f32 = *flagp;
    int blk = blockIdx.x;
    int b = blk >> 2, ch = blk & 3;
    int f = threadIdx.x;
    float s = 0.f;
    int n0 = ch * 64;
    for (int n = n0; n < n0 + 64; n++) s += ldin(x, ((long long)(b * 256 + n)) * 256 + f, f32);
    Sp[blk * 256 + f] = s;
}

// ---- Wc = W0 + 0.5*W1 (fp32) -----------------------------------------------
__global__ void k_wc(const void* __restrict__ chw, float* __restrict__ Wc,
                     const int* __restrict__ flagp) {
    int f32 = *flagp;
    int i = blockIdx.x * 256 + threadIdx.x;
    Wc[i] = ldin(chw, i, f32) + 0.5f * ldin(chw, 65536 + i, f32);
}

// ---- tb partials: tbp[b*8+fc][o] over f in [fc*32, fc*32+32) ---------------
__global__ void k_tb1(const float* __restrict__ Sp, const void* __restrict__ chw,
                      float* __restrict__ tbp, const int* __restrict__ flagp) {
    int f32 = *flagp;
    int blk = blockIdx.x;
    int b = blk >> 3, fc = blk & 7;
    int o = threadIdx.x;
    float acc = 0.f;
    const float cs = 1.0f / 512.0f;
    int f0 = fc * 32;
    for (int f = f0; f < f0 + 32; f++) {
        float s = Sp[(b * 4 + 0) * 256 + f] + Sp[(b * 4 + 1) * 256 + f] +
                  Sp[(b * 4 + 2) * 256 + f] + Sp[(b * 4 + 3) * 256 + f];
        acc = fmaf(s * cs, ldin(chw, 65536 + f * 256 + o, f32), acc);
    }
    tbp[blk * 256 + o] = acc;
}

// ---- tb[b][o] = chb[o] + sum_fc tbp ---------------------------------------
__global__ void k_tb2(const float* __restrict__ tbp, const void* __restrict__ chb,
                      float* __restrict__ tb, const int* __restrict__ flagp) {
    int f32 = *flagp;
    int b = blockIdx.x, o = threadIdx.x;
    float acc = ldin(chb, o, f32);
#pragma unroll
    for (int fc = 0; fc < 8; fc++) acc += tbp[(b * 8 + fc) * 256 + o];
    tb[b * 256 + o] = acc;
}

// ---- cheb row GEMM + LayerNorm(256) -> M1 fp16 -----------------------------
__global__ void k_cheb_ln(const void* __restrict__ x, const float* __restrict__ Wc,
                          const float* __restrict__ tb, const void* __restrict__ g,
                          const void* __restrict__ bb, __half* __restrict__ out,
                          const int* __restrict__ flagp) {
    __shared__ float xr[256];
    __shared__ float red1[4], red2[4];
    int f32 = *flagp;
    int row = blockIdx.x;
    int b = row >> 8;
    int o = threadIdx.x;
    xr[o] = ldin(x, row * 256 + o, f32);
    __syncthreads();
    float acc = tb[b * 256 + o];
    const float4* x4 = (const float4*)xr;
#pragma unroll 8
    for (int q = 0; q < 64; q++) {
        float4 xv = x4[q];
        int f = q * 4;
        acc = fmaf(xv.x, Wc[f * 256 + o], acc);
        acc = fmaf(xv.y, Wc[(f + 1) * 256 + o], acc);
        acc = fmaf(xv.z, Wc[(f + 2) * 256 + o], acc);
        acc = fmaf(xv.w, Wc[(f + 3) * 256 + o], acc);
    }
    float s1 = acc, s2 = acc * acc;
    for (int off = 32; off >= 1; off >>= 1) {
        s1 += __shfl_xor(s1, off, 64);
        s2 += __shfl_xor(s2, off, 64);
    }
    if ((o & 63) == 0) { red1[o >> 6] = s1; red2[o >> 6] = s2; }
    __syncthreads();
    float S1 = red1[0] + red1[1] + red1[2] + red1[3];
    float S2 = red2[0] + red2[1] + red2[2] + red2[3];
    float m = S1 * (1.0f / 256.0f);
    float var = S2 * (1.0f / 256.0f) - m * m;
    float rstd = rsqrtf(var + 1e-5f);
    out[row * 256 + o] = __float2half((acc - m) * rstd * ldin(g, o, f32) + ldin(bb, o, f32));
}

// ---- coalesced tiled transpose: WT[ld][f][j] = wih[ld][j][f] (fp16) --------
__global__ void k_wih_t(const void* __restrict__ wih, __half* __restrict__ WT,
                        const int* __restrict__ flagp) {
    __shared__ __half tile[64][65];
    int f32 = *flagp;
    int ld = blockIdx.z;
    int jt = blockIdx.y * 64;
    int ft = blockIdx.x * 64;
    int lane = threadIdx.x & 63;
    int wv = threadIdx.x >> 6;
#pragma unroll
    for (int r = wv; r < 64; r += 4)
        tile[r][lane] = __float2half(ldin(wih, ((long long)(ld * 512 + jt + r)) * 256 + ft + lane, f32));
    __syncthreads();
#pragma unroll
    for (int r = wv; r < 64; r += 4)
        WT[((long long)ld * 256 + ft + r) * 512 + jt + lane] = tile[lane][r];
}

// ---- gin[d][b][t][j] = in[b][t] @ WihT + bih + bhh (fp16 store) ------------
__global__ __launch_bounds__(512) void k_gin(const __half* __restrict__ in,
                                             const __half* __restrict__ WT,
                                             const void* __restrict__ bih,
                                             const void* __restrict__ bhh,
                                             __half* __restrict__ gin, int l,
                                             const int* __restrict__ flagp) {
    __shared__ float inl[16 * 256];
    int f32 = *flagp;
    int d = blockIdx.x >> 7;
    int rb = (blockIdx.x & 127) * 16;
    int j = threadIdx.x;
    const __half2* src = (const __half2*)(in + (size_t)rb * 256);
    float2* dst = (float2*)inl;
#pragma unroll
    for (int q = 0; q < 4; q++)
        dst[j + q * 512] = __half22float2(src[j + q * 512]);
    __syncthreads();
    int ld = l * 2 + d;
    float bias = ldin(bih, ld * 512 + j, f32) + ldin(bhh, ld * 512 + j, f32);
    float acc[16];
#pragma unroll
    for (int r = 0; r < 16; r++) acc[r] = bias;
    const __half* W = WT + (size_t)ld * 131072;
    for (int fq = 0; fq < 64; fq++) {
        int f = fq * 4;
        float w0 = __half2float(W[(f + 0) * 512 + j]);
        float w1 = __half2float(W[(f + 1) * 512 + j]);
        float w2 = __half2float(W[(f + 2) * 512 + j]);
        float w3 = __half2float(W[(f + 3) * 512 + j]);
#pragma unroll
        for (int r = 0; r < 16; r++) {
            const float4 iv = ((const float4*)(inl + r * 256))[fq];
            acc[r] = fmaf(iv.x, w0, fmaf(iv.y, w1, fmaf(iv.z, w2, fmaf(iv.w, w3, acc[r]))));
        }
    }
    int b = rb >> 8;
    int t0 = rb & 255;
#pragma unroll
    for (int r = 0; r < 16; r++)
        gin[(size_t)(((d * 8 + b) * 256) + (t0 + r)) * 512 + j] = __float2half(acc[r]);
}

// ---- LSTM recurrence: one block per (dir, batch) ---------------------------
// h kept fp16 in LDS; GEMV via v_dot2_f32_f16 (fp32 accumulate). 4 acc chains.
// Distributed pre-activation; reducer (tid<128) c/h update; batched h stores.
__global__ __launch_bounds__(512) __attribute__((amdgpu_waves_per_eu(1, 2)))
void k_lstm(const __half* __restrict__ gin, const void* __restrict__ whh,
            long long woff, __half* __restrict__ hcat, const int* __restrict__ flagp) {
    __shared__ __align__(16) __half h_lds[2][128];
    __shared__ float gate[512];
    int f32 = *flagp;
    int d = blockIdx.x >> 3;
    int b = blockIdx.x & 7;
    int tid = threadIdx.x;
    int gtype = tid >> 7; // 0:i 1:f 2:g 3:o

    // Whh row (128 weights) -> 64 half2 registers
    h2_t w[64];
    if (f32) {
        const float2* p = (const float2*)((const float*)whh + woff + (size_t)(d * 512 + tid) * 128);
#pragma unroll
        for (int q = 0; q < 64; q++) {
            float2 u = p[q];
            w[q] = h2_t{(_Float16)u.x, (_Float16)u.y};
        }
    } else {
        const u32* p = (const u32*)((const u16*)whh + woff + (size_t)(d * 512 + tid) * 128);
#pragma unroll
        for (int q = 0; q < 64; q++) {
            u32 u = p[q];
            w[q] = h2_t{(_Float16)__uint_as_float(u << 16),
                        (_Float16)__uint_as_float(u & 0xffff0000u)};
        }
    }

    if (tid < 128) h_lds[0][tid] = __float2half(0.0f);
    float c = 0.0f;
    float hv8[8];
    const __half* gbase = gin + (size_t)((d * 8 + b) * 256) * 512 + tid;
    __syncthreads();

    int cur = 0;
    for (int t8 = 0; t8 < 32; t8++) {
#pragma unroll
        for (int s = 0; s < 8; s++) {
            int t = t8 * 8 + s;
            int tt = d ? (255 - t) : t;
            float gv = __half2float(gbase[(size_t)tt * 512]);
            float a0 = 0.f, a1 = 0.f, a2 = 0.f, a3 = 0.f;
            const uint4* h4 = (const uint4*)h_lds[cur];
#pragma unroll
            for (int q = 0; q < 16; q++) {
                uint4 u = h4[q];
                a0 = __builtin_amdgcn_fdot2(as_h2(u.x), w[q * 4 + 0], a0, false);
                a1 = __builtin_amdgcn_fdot2(as_h2(u.y), w[q * 4 + 1], a1, false);
                a2 = __builtin_amdgcn_fdot2(as_h2(u.z), w[q * 4 + 2], a2, false);
                a3 = __builtin_amdgcn_fdot2(as_h2(u.w), w[q * 4 + 3], a3, false);
            }
            float pre = (a0 + a1) + (a2 + a3) + gv;
            gate[tid] = (gtype == 2) ? tanh_f(pre) : sigm(pre);
            __syncthreads();
            if (tid < 128) {
                c = gate[tid + 128] * c + gate[tid] * gate[tid + 256];
                float hv = gate[tid + 384] * tanh_f(c);
                h_lds[cur ^ 1][tid] = __float2half(hv);
                hv8[s] = hv;
            }
            __syncthreads();
            cur ^= 1;
        }
        if (tid < 128) {
            int tbase = t8 * 8;
#pragma unroll
            for (int s = 0; s < 8; s++) {
                int tt = d ? (255 - (tbase + s)) : (tbase + s);
                hcat[(size_t)(b * 256 + tt) * 256 + d * 128 + tid] = __float2half(hv8[s]);
            }
        }
    }
}

// ---- final LayerNorm(256): M2 -> M1 (lnout fp16) + output 2 ----------------
__global__ void k_ln_out(const __half* __restrict__ in, const void* __restrict__ g,
                         const void* __restrict__ bb, __half* __restrict__ lnout,
                         void* out, const int* __restrict__ flagp) {
    __shared__ float red1[4], red2[4];
    int f32 = *flagp;
    int row = blockIdx.x;
    int o = threadIdx.x;
    float v = __half2float(in[row * 256 + o]);
    float s1 = v, s2 = v * v;
    for (int off = 32; off >= 1; off >>= 1) {
        s1 += __shfl_xor(s1, off, 64);
        s2 += __shfl_xor(s2, off, 64);
    }
    if ((o & 63) == 0) { red1[o >> 6] = s1; red2[o >> 6] = s2; }
    __syncthreads();
    float S1 = red1[0] + red1[1] + red1[2] + red1[3];
    float S2 = red2[0] + red2[1] + red2[2] + red2[3];
    float m = S1 * (1.0f / 256.0f);
    float var = S2 * (1.0f / 256.0f) - m * m;
    float rstd = rsqrtf(var + 1e-5f);
    float r = (v - m) * rstd * ldin(g, o, f32) + ldin(bb, o, f32);
    lnout[row * 256 + o] = __float2half(r);
    store_out(out, 526336LL + (long long)row * 256 + o, r, f32);
}

// ---- agg[b][j] = mean_t lnout[b][t][j] -> output 0 -------------------------
__global__ void k_agg(const __half* __restrict__ lnout, void* out,
                      const int* __restrict__ flagp) {
    int b = blockIdx.x, j = threadIdx.x;
    float s = 0.f;
    for (int t = 0; t < 256; t++) s += __half2float(lnout[(size_t)(b * 256 + t) * 256 + j]);
    store_out(out, (long long)b * 256 + j, s * (1.0f / 256.0f), *flagp);
}

extern "C" void kernel_launch(void* const* d_in, const int* in_sizes, int n_in,
                              void* d_out, int out_size, void* d_ws, size_t ws_size,
                              hipStream_t stream) {
    char* wsb = (char*)d_ws;
    int*    flag = (int*)(wsb + WB_FLAG);
    float*  Sp   = (float*)(wsb + WB_S);
    float*  tb   = (float*)(wsb + WB_TB);
    float*  tbp  = (float*)(wsb + WB_TBP);
    float*  Wc   = (float*)(wsb + WB_WC);
    __half* WT   = (__half*)(wsb + WB_WT);
    __half* M1   = (__half*)(wsb + WB_M1);
    __half* M2   = (__half*)(wsb + WB_M2);
    __half* GIN  = (__half*)(wsb + WB_GIN);

    const void* x   = d_in[0];
    const void* chw = d_in[5];
    const void* chb = d_in[6];
    const void* lcg = d_in[7];
    const void* lcb = d_in[8];
    const void* wih = d_in[9];
    const void* whh = d_in[10];
    const void* bih = d_in[11];
    const void* bhh = d_in[12];
    const void* log_ = d_in[13];
    const void* lob  = d_in[14];

    k_detect<<<1, 256, 0, stream>>>((const u32*)x, flag);
    k_fill_tg<<<512, 256, 0, stream>>>(d_out, flag);
    k_colsum<<<32, 256, 0, stream>>>(x, Sp, flag);
    k_wc<<<256, 256, 0, stream>>>(chw, Wc, flag);
    k_tb1<<<64, 256, 0, stream>>>(Sp, chw, tbp, flag);
    k_tb2<<<8, 256, 0, stream>>>(tbp, chb, tb, flag);
    k_cheb_ln<<<2048, 256, 0, stream>>>(x, Wc, tb, lcg, lcb, M1, flag);
    k_wih_t<<<dim3(4, 8, 4), 256, 0, stream>>>(wih, WT, flag);
    // layer 0
    k_gin<<<256, 512, 0, stream>>>(M1, WT, bih, bhh, GIN, 0, flag);
    k_lstm<<<16, 512, 0, stream>>>(GIN, whh, 0LL, M2, flag);
    // layer 1
    k_gin<<<256, 512, 0, stream>>>(M2, WT, bih, bhh, GIN, 1, flag);
    k_lstm<<<16, 512, 0, stream>>>(GIN, whh, 131072LL, M2, flag);
    k_ln_out<<<2048, 256, 0, stream>>>(M2, log_, lob, M1, d_out, flag);
    k_agg<<<8, 256, 0, stream>>>(M1, d_out, flag);
}